// Round 17
// baseline (290.040 us; speedup 1.0000x reference)
//
#include <hip/hip_runtime.h>
#include <cmath>

// x [B=4096][T=512][D=4], H=32, gates 4H=128 (PyTorch order i,f,g,o).
constexpr int T   = 512;
constexpr int D   = 4;
constexpr int H   = 32;
constexpr int BT  = 16;    // batch cols per block — ALL real
constexpr int BLK = 256;   // 4 waves: (layer, unit-half)

constexpr float LOG2E     = 1.44269504088896340736f;
constexpr float NEG2LOG2E = -2.88539008177792681472f;

constexpr int XSTRIDE = 4104;   // x frag col stride (shorts)
constexpr int HSTR    = 40;     // h row stride (shorts)

typedef short bf8 __attribute__((ext_vector_type(8)));  // 8 bf16 (4 VGPRs)
typedef short s4v __attribute__((ext_vector_type(4)));  // 4 bf16 (8B)
typedef float f4  __attribute__((ext_vector_type(4)));  // MFMA C/D

// fp32 -> bf16 round-to-nearest-even
static __device__ __forceinline__ short bf16_rtn(float v) {
    unsigned u = __float_as_uint(v);
    u += 0x7FFFu + ((u >> 16) & 1u);
    return (short)(u >> 16);
}

// R16 body (wave = (layer, unit-half) owns all 4 gate tiles; lane-local
// i,f,g,o in C/D regs; single-product bf16 MFMAs, exp2-folded weights;
// plain-bf16 h; x pre-staged as padded fragments; 1 barrier/iter) with
// the loop peeled: i=0 (L1-only) and i=T (L2-only + head state) are
// dedicated bodies; the 511 steady iterations are fully branchless.
__global__ __launch_bounds__(BLK, 1) void lstm_bf16f(
    const float* __restrict__ x,
    const float* __restrict__ W_ih0, const float* __restrict__ W_hh0,
    const float* __restrict__ b_ih0, const float* __restrict__ b_hh0,
    const float* __restrict__ W_ih1, const float* __restrict__ W_hh1,
    const float* __restrict__ b_ih1, const float* __restrict__ b_hh1,
    const float* __restrict__ W_out, const float* __restrict__ b_out,
    float* __restrict__ out)
{
    __shared__ __align__(16) short xbf[16 * XSTRIDE];   // 131.3 KB staged x frags
    __shared__ __align__(16) short h0b[2][16][HSTR];    // h, [buf][col][unit]
    __shared__ __align__(16) short h1b[2][16][HSTR];
    __shared__ __align__(16) float h1f[16][36];         // final h1 fp32 for the head

    const int tid   = threadIdx.x;
    const int w     = tid >> 6;
    const int lane  = tid & 63;
    const int q     = lane >> 4;       // quad
    const int nl    = lane & 15;       // batch col (all real)
    const int layer = w >> 1;          // 0: L1, 1: L2
    const int ug    = (w & 1) << 4;    // unit group offset 0 / 16
    const int b0    = blockIdx.x * BT;

    // ---- stage x -> zero-padded bf16 fragments (col-minor: clean banks) ----
    for (int idx = tid; idx < 16 * T; idx += BLK) {
        const int col = idx & 15;
        const int t   = idx >> 4;
        float4 xv = *(const float4*)(x + ((size_t)(b0 + col) * T + t) * D);
        bf8 v = {0, 0, 0, 0, 0, 0, 0, 0};
        v[0] = bf16_rtn(xv.x); v[1] = bf16_rtn(xv.y);
        v[2] = bf16_rtn(xv.z); v[3] = bf16_rtn(xv.w);
        *(bf8*)&xbf[col * XSTRIDE + t * 8] = v;
    }
    // zero both h buffers
    for (int idx = tid; idx < 2 * 16 * HSTR; idx += BLK) {
        (&h0b[0][0][0])[idx] = 0;
        (&h1b[0][0][0])[idx] = 0;
    }

    // ---- weights: tile g = gate type. A-frag row = 32g + ug + nl, k = 8q+j.
    const float* W1 = layer ? W_ih1 : W_hh0;
    bf8 w1[4], w2[4];
    f4  bias[4];
    #pragma unroll
    for (int g = 0; g < 4; ++g) {
        const float sc = (g == 2) ? NEG2LOG2E : -LOG2E;
        const int row = 32 * g + ug + nl;
        #pragma unroll
        for (int j = 0; j < 8; ++j) {
            w1[g][j] = bf16_rtn(W1[row * H + 8 * q + j] * sc);
            float v2 = layer ? W_hh1[row * H + 8 * q + j]
                             : ((q == 0 && j < 4) ? W_ih0[row * D + j] : 0.0f);
            w2[g][j] = bf16_rtn(v2 * sc);
        }
        #pragma unroll
        for (int r = 0; r < 4; ++r) {
            const int gr = 32 * g + ug + 4 * q + r;
            bias[g][r] = sc * (layer ? (b_ih1[gr] + b_hh1[gr])
                                     : (b_ih0[gr] + b_hh0[gr]));
        }
    }

    float c[4] = {0.0f, 0.0f, 0.0f, 0.0f};   // cell state, fp32, lane-local
    const short* xcol = &xbf[nl * XSTRIDE];

    __syncthreads();

    // gate MFMAs + state update, no activity predicates (steady state)
    auto gates = [&](const int i, const int rb, f4 (&acc)[4]) {
        bf8 b2;
        if (layer == 0) b2 = *(const bf8*)&xcol[i * 8];            // x(i)
        else            b2 = *(const bf8*)&h1b[rb][nl][8 * q];     // h1(i-2)
        bf8 b1 = *(const bf8*)&h0b[rb][nl][8 * q];                 // h0(i-1)
        #pragma unroll
        for (int g = 0; g < 4; ++g) {
            f4 A = __builtin_amdgcn_mfma_f32_16x16x32_bf16(w2[g], b2, bias[g], 0, 0, 0);
            A    = __builtin_amdgcn_mfma_f32_16x16x32_bf16(w1[g], b1, A,       0, 0, 0);
            acc[g] = A;
        }
    };
    auto update = [&](const f4 (&acc)[4], float (&hv)[4]) {
        #pragma unroll
        for (int r = 0; r < 4; ++r) {
            float ei = __builtin_amdgcn_exp2f(acc[0][r]);
            float ef = __builtin_amdgcn_exp2f(acc[1][r]);
            float eg = __builtin_amdgcn_exp2f(acc[2][r]);
            float eo = __builtin_amdgcn_exp2f(acc[3][r]);
            float D1 = 1.0f + ef;
            float D2 = (1.0f + ei) * (1.0f + eg);
            float rD = __builtin_amdgcn_rcpf(D1 * D2);
            c[r] = (fmaf(c[r], D2, (1.0f - eg) * D1)) * rD;
            float ec = __builtin_amdgcn_exp2f(c[r] * NEG2LOG2E);
            float ro = __builtin_amdgcn_rcpf((1.0f + eo) * (1.0f + ec));
            hv[r] = (1.0f - ec) * ro;
        }
    };
    auto store_h = [&](const float (&hv)[4], const int wb) {
        s4v hh;
        hh[0] = bf16_rtn(hv[0]); hh[1] = bf16_rtn(hv[1]);
        hh[2] = bf16_rtn(hv[2]); hh[3] = bf16_rtn(hv[3]);
        if (layer == 0) *(s4v*)&h0b[wb][nl][ug + 4 * q] = hh;
        else            *(s4v*)&h1b[wb][nl][ug + 4 * q] = hh;
    };

    // ---- i = 0: L1 only ----
    {
        f4 acc[4]; float hv[4];
        gates(0, 0, acc);
        if (layer == 0) { update(acc, hv); store_h(hv, 1); }
        __syncthreads();
    }
    // ---- steady: i = 1 .. 511, branchless ----
    #pragma unroll 1
    for (int i = 1; i < T - 1; i += 2) {      // 255 pairs: (odd rb=1, even rb=0)
        {
            f4 acc[4]; float hv[4];
            gates(i, 1, acc); update(acc, hv); store_h(hv, 0);
            __syncthreads();
        }
        {
            f4 acc[4]; float hv[4];
            gates(i + 1, 0, acc); update(acc, hv); store_h(hv, 1);
            __syncthreads();
        }
    }
    {   // i = 511 (rb = 1)
        f4 acc[4]; float hv[4];
        gates(T - 1, 1, acc); update(acc, hv); store_h(hv, 0);
        __syncthreads();
    }
    // ---- i = T: L2 only (flush step 511) + head state ----
    {
        f4 acc[4]; float hv[4];
        if (layer == 1) {
            bf8 b2 = *(const bf8*)&h1b[0][nl][8 * q];   // h1(510)
            bf8 b1 = *(const bf8*)&h0b[0][nl][8 * q];   // h0(511)
            #pragma unroll
            for (int g = 0; g < 4; ++g) {
                f4 A = __builtin_amdgcn_mfma_f32_16x16x32_bf16(w2[g], b2, bias[g], 0, 0, 0);
                A    = __builtin_amdgcn_mfma_f32_16x16x32_bf16(w1[g], b1, A,       0, 0, 0);
                acc[g] = A;
            }
            update(acc, hv);
            float4 hw; hw.x = hv[0]; hw.y = hv[1]; hw.z = hv[2]; hw.w = hv[3];
            *(float4*)&h1f[nl][ug + 4 * q] = hw;        // h1(511), fp32
        }
        __syncthreads();
    }

    // ---- output head: out[b0+n] = b_out + W_out . h1(T-1) ----
    if (tid < BT) {
        float acc = b_out[0];
        #pragma unroll
        for (int u = 0; u < H; ++u) acc = fmaf(W_out[u], h1f[tid][u], acc);
        out[b0 + tid] = acc;
    }
}

extern "C" void kernel_launch(void* const* d_in, const int* in_sizes, int n_in,
                              void* d_out, int out_size, void* d_ws, size_t ws_size,
                              hipStream_t stream) {
    const float* x     = (const float*)d_in[0];
    const float* W_ih0 = (const float*)d_in[1];
    const float* W_hh0 = (const float*)d_in[2];
    const float* b_ih0 = (const float*)d_in[3];
    const float* b_hh0 = (const float*)d_in[4];
    const float* W_ih1 = (const float*)d_in[5];
    const float* W_hh1 = (const float*)d_in[6];
    const float* b_ih1 = (const float*)d_in[7];
    const float* b_hh1 = (const float*)d_in[8];
    const float* W_out = (const float*)d_in[9];
    const float* b_out = (const float*)d_in[10];
    float* out = (float*)d_out;

    const int B = out_size;          // 4096
    lstm_bf16f<<<B / BT, BLK, 0, stream>>>(x, W_ih0, W_hh0, b_ih0, b_hh0,
                                           W_ih1, W_hh1, b_ih1, b_hh1,
                                           W_out, b_out, out);
}